// Round 1
// baseline (5851.735 us; speedup 1.0000x reference)
//
#include <hip/hip_runtime.h>

// HMM scaled-forward: L sequential steps of (per m,b) matvec + renormalize.
// One workgroup per (m,b) sequence: 128 workgroups x 512 threads.
// u (unnormalized sf) lives in LDS; normalization deferred into next matvec.

constexpr int Q = 512;   // states
constexpr int L = 512;   // seq len
constexpr int M = 2;     // models
constexpr int B = 64;    // batch
constexpr float EPS = 1e-16f;

__global__ __launch_bounds__(Q) void hmm_forward(
    const float* __restrict__ emis,   // (L, M, B, Q)
    const float* __restrict__ Aall,   // (M, Q, Q)
    const float* __restrict__ initd,  // (M, Q)
    float* __restrict__ out)          // (M, B)
{
    const int bid  = blockIdx.x;      // m*B + b
    const int m    = bid / B;
    const int k    = threadIdx.x;     // output state owned by this thread
    const int lane = k & 63;
    const int wid  = k >> 6;

    const float* __restrict__ Am = Aall + (size_t)m * Q * Q;
    const float* __restrict__ E  = emis + (size_t)bid * Q;  // (t=0, m, b, :)
    const size_t stepStride = (size_t)M * B * Q;

    __shared__ float u_lds[Q];   // unnormalized sf from previous step
    __shared__ float red[8];     // per-wave partial sums

    // ---- step 0: u0 = max(E0,eps) * max(init,eps) ----
    float e    = fmaxf(E[k], EPS);
    float r    = fmaxf(initd[m * Q + k], EPS);
    float uval = e * r;

    float ll   = 0.0f;
    float invS = 1.0f;

    for (int t = 1; t <= L; ++t) {
        // wave-level sum of uval (all lanes end with the wave total)
        float ws = uval;
        #pragma unroll
        for (int off = 32; off >= 1; off >>= 1)
            ws += __shfl_xor(ws, off, 64);

        __syncthreads();               // prior matvec reads of u_lds/red done
        u_lds[k] = uval;
        if (lane == 0) red[wid] = ws;
        __syncthreads();               // u_lds + red published

        float S = 0.0f;
        #pragma unroll
        for (int w = 0; w < 8; ++w) S += red[w];
        ll  += __logf(S);              // accumulate log-likelihood
        invS = 1.0f / S;
        if (t == L) break;             // last step: only the reduction remains

        // matvec: acc = sum_q u[q] * A[m][q][k]   (column k, coalesced across lanes)
        float acc = 0.0f;
        #pragma unroll 8
        for (int q = 0; q < Q; ++q)
            acc = fmaf(u_lds[q], Am[q * Q + k], acc);

        float rr = fmaxf(acc * invS, EPS);                    // R clamped
        float ee = fmaxf(E[(size_t)t * stepStride + k], EPS); // E clamped
        uval = ee * rr;
    }

    if (k == 0) out[bid] = ll;
}

extern "C" void kernel_launch(void* const* d_in, const int* in_sizes, int n_in,
                              void* d_out, int out_size, void* d_ws, size_t ws_size,
                              hipStream_t stream) {
    const float* emis  = (const float*)d_in[0];  // (L, M, B, Q)
    const float* A     = (const float*)d_in[1];  // (M, Q, Q)
    const float* initd = (const float*)d_in[2];  // (M, Q)
    float* out = (float*)d_out;                  // (M, B)

    hipLaunchKernelGGL(hmm_forward, dim3(M * B), dim3(Q), 0, stream,
                       emis, A, initd, out);
}

// Round 2
// 976.844 us; speedup vs baseline: 5.9905x; 5.9905x over previous
//
#include <hip/hip_runtime.h>

// HMM scaled-forward, A resident on-chip.
// Grid: 128 wgs (one per (m,b)), 1024 threads = 8 q-groups x 128 col-threads.
// A[m] (512x512) is packed once (pack_A) into f16 q-pair words; each thread
// owns 4 cols x 32 q-pairs = 128 words: 24 16B-chunks in VGPRs + 8 chunks in
// LDS (128 KB). Per step: dot2 accumulate -> 8x512 LDS reduction -> renorm ->
// new u (f16 pairs) in LDS. No per-step global A traffic, no cross-wg sync.

typedef _Float16 h2 __attribute__((ext_vector_type(2)));
typedef _Float16 h8 __attribute__((ext_vector_type(8)));

constexpr int Q = 512;
constexpr int L = 512;
constexpr int M = 2;
constexpr int B = 64;
constexpr int NTH = 1024;     // 8 q-groups x 128 col-threads
constexpr int CHUNKS = 32;    // 16B chunks per thread (128 half2 words)
constexpr int REG_CH = 24;    // chunks in VGPRs (96 regs)
constexpr int LDS_CH = 8;     // chunks in LDS (128 KB)
constexpr float EPS = 1e-16f;

constexpr int LDSA_BYTES = LDS_CH * NTH * 16;     // 131072
constexpr int LDSU_OFF   = LDSA_BYTES;            // 256 h2 words = 1 KB
constexpr int RED_OFF    = LDSU_OFF + 1024;       // 8 x 512 f32 = 16 KB
constexpr int RED2_OFF   = RED_OFF + 8 * Q * 4;
constexpr int SMEM_BYTES = RED2_OFF + 16;         // 148496 B

__device__ __forceinline__ float fdot2(h2 a, h2 b, float c) {
#if __has_builtin(__builtin_amdgcn_fdot2)
    return __builtin_amdgcn_fdot2(a, b, c, false);
#else
    return fmaf((float)a.x, (float)b.x, fmaf((float)a.y, (float)b.y, c));
#endif
}

// pack A (M,Q,Q) f32 -> per-thread chunk layout, f16 pairs over q.
// chunk c of thread t (qg=t>>7, ct=t&127): word j = (A[m][qg*64+2c][4ct+j],
// A[m][qg*64+2c+1][4ct+j]), stored at wsA[(m*32+c)*1024 + t].
__global__ __launch_bounds__(256) void pack_A(const float* __restrict__ A,
                                              uint4* __restrict__ wsA) {
    int idx = blockIdx.x * 256 + threadIdx.x;
    int t = idx & (NTH - 1);
    int c = (idx >> 10) & (CHUNKS - 1);
    int m = idx >> 15;
    int qg = t >> 7, ct = t & 127;
    int q0 = qg * 64 + 2 * c;
    const float* a0 = A + ((size_t)m * Q + q0) * Q + 4 * ct;
    float4 r0 = *(const float4*)a0;
    float4 r1 = *(const float4*)(a0 + Q);
    union { h2 w[4]; uint4 v; } cv;
    cv.w[0].x = (_Float16)r0.x; cv.w[0].y = (_Float16)r1.x;
    cv.w[1].x = (_Float16)r0.y; cv.w[1].y = (_Float16)r1.y;
    cv.w[2].x = (_Float16)r0.z; cv.w[2].y = (_Float16)r1.z;
    cv.w[3].x = (_Float16)r0.w; cv.w[3].y = (_Float16)r1.w;
    wsA[idx] = cv.v;
}

__global__ __launch_bounds__(NTH) void hmm_fwd(
    const float* __restrict__ emis,   // (L, M, B, Q)
    const uint4* __restrict__ wsA,    // packed A
    const float* __restrict__ initd,  // (M, Q)
    float* __restrict__ out)          // (M, B)
{
    extern __shared__ char smem[];
    uint4* ldsA = (uint4*)smem;
    h2*    ldsU = (h2*)(smem + LDSU_OFF);
    float* red  = (float*)(smem + RED_OFF);
    float* red2 = (float*)(smem + RED2_OFF);

    const int t   = threadIdx.x;
    const int bid = blockIdx.x;       // m*B + b
    const int m   = bid >> 6;
    const int qg  = t >> 7;
    const int ct  = t & 127;

    // ---- one-time A staging: 24 chunks -> VGPRs, 8 chunks -> LDS ----
    const uint4* wa = wsA + (size_t)m * CHUNKS * NTH + t;
    h8 areg[REG_CH];
    #pragma unroll
    for (int c = 0; c < REG_CH; ++c)
        areg[c] = *(const h8*)(wa + (size_t)c * NTH);
    #pragma unroll
    for (int s = 0; s < LDS_CH; ++s)
        ldsA[s * NTH + t] = wa[(size_t)(REG_CH + s) * NTH];

    const float* E = emis + (size_t)bid * Q;       // (t=0, m, b, :)
    const size_t stepStride = (size_t)M * B * Q;

    // ---- init step: u0 = max(E0,eps) * max(init,eps) ----
    if (t < 256) {
        float2 ip = *(const float2*)(initd + m * Q + 2 * t);
        float2 ep = *(const float2*)(E + 2 * t);
        float u0 = fmaxf(ep.x, EPS) * fmaxf(ip.x, EPS);
        float u1 = fmaxf(ep.y, EPS) * fmaxf(ip.y, EPS);
        h2 w; w.x = (_Float16)u0; w.y = (_Float16)u1;
        ldsU[t] = w;
        float s = u0 + u1;
        #pragma unroll
        for (int off = 32; off >= 1; off >>= 1) s += __shfl_xor(s, off, 64);
        if ((t & 63) == 0) red2[t >> 6] = s;
    }
    __syncthreads();   // also covers ldsA staging before first dot phase

    float4 r2 = *(const float4*)red2;
    float S = (r2.x + r2.y) + (r2.z + r2.w);
    float invS = 1.0f / S;
    float ll = __logf(S);

    for (int step = 1; step < L; ++step) {
        // E prefetch for phase2 (hidden under the dot phase)
        float2 ep; ep.x = 0.f; ep.y = 0.f;
        if (t < 256)
            ep = *(const float2*)(E + (size_t)step * stepStride + 2 * t);

        // ---- phase1: acc_j = sum_{qp in my qg} u[qp] . A[qp][4ct+j] ----
        float a0 = 0.f, a1 = 0.f, a2 = 0.f, a3 = 0.f;
        const h8* uq8 = (const h8*)(ldsU + qg * 32);  // wave-uniform broadcast
        #pragma unroll
        for (int i = 0; i < 8; ++i) {
            h8 uw = uq8[i];
            h2 up[4] = {uw.lo.lo, uw.lo.hi, uw.hi.lo, uw.hi.hi};
            #pragma unroll
            for (int p = 0; p < 4; ++p) {
                const int c = i * 4 + p;
                h8 a;
                if (c < REG_CH) a = areg[c];
                else            a = *(const h8*)(ldsA + (c - REG_CH) * NTH + t);
                a0 = fdot2(a.lo.lo, up[p], a0);
                a1 = fdot2(a.lo.hi, up[p], a1);
                a2 = fdot2(a.hi.lo, up[p], a2);
                a3 = fdot2(a.hi.hi, up[p], a3);
            }
        }
        float4 rv; rv.x = a0; rv.y = a1; rv.z = a2; rv.w = a3;
        *(float4*)(red + qg * Q + 4 * ct) = rv;      // red[qg][4ct..4ct+3]
        __syncthreads();

        // ---- phase2 (t<256): reduce 8 qg, renorm, clamp, new u ----
        if (t < 256) {
            float r0 = 0.f, r1 = 0.f;
            #pragma unroll
            for (int g = 0; g < 8; ++g) {
                float2 rp = *(const float2*)(red + g * Q + 2 * t);
                r0 += rp.x; r1 += rp.y;
            }
            float u0 = fmaxf(ep.x, EPS) * fmaxf(r0 * invS, EPS);
            float u1 = fmaxf(ep.y, EPS) * fmaxf(r1 * invS, EPS);
            h2 w; w.x = (_Float16)u0; w.y = (_Float16)u1;
            ldsU[t] = w;
            float s = u0 + u1;
            #pragma unroll
            for (int off = 32; off >= 1; off >>= 1) s += __shfl_xor(s, off, 64);
            if ((t & 63) == 0) red2[t >> 6] = s;
        }
        __syncthreads();

        r2 = *(const float4*)red2;
        S = (r2.x + r2.y) + (r2.z + r2.w);
        invS = 1.0f / S;
        ll += __logf(S);
    }

    if (t == 0) out[bid] = ll;
}

// ---- fallback (round-1 kernel) if ws is too small for packed A ----
__global__ __launch_bounds__(512) void hmm_forward_fb(
    const float* __restrict__ emis, const float* __restrict__ Aall,
    const float* __restrict__ initd, float* __restrict__ out)
{
    const int bid = blockIdx.x;
    const int m = bid / B;
    const int k = threadIdx.x;
    const int lane = k & 63, wid = k >> 6;
    const float* Am = Aall + (size_t)m * Q * Q;
    const float* E = emis + (size_t)bid * Q;
    const size_t stepStride = (size_t)M * B * Q;
    __shared__ float u_lds[Q];
    __shared__ float redf[8];
    float e = fmaxf(E[k], EPS);
    float r = fmaxf(initd[m * Q + k], EPS);
    float uval = e * r;
    float ll = 0.0f, invS = 1.0f;
    for (int t = 1; t <= L; ++t) {
        float ws = uval;
        #pragma unroll
        for (int off = 32; off >= 1; off >>= 1) ws += __shfl_xor(ws, off, 64);
        __syncthreads();
        u_lds[k] = uval;
        if (lane == 0) redf[wid] = ws;
        __syncthreads();
        float S = 0.0f;
        #pragma unroll
        for (int w = 0; w < 8; ++w) S += redf[w];
        ll += __logf(S);
        invS = 1.0f / S;
        if (t == L) break;
        float acc = 0.0f;
        #pragma unroll 8
        for (int q = 0; q < Q; ++q)
            acc = fmaf(u_lds[q], Am[q * Q + k], acc);
        float rr = fmaxf(acc * invS, EPS);
        float ee = fmaxf(E[(size_t)t * stepStride + k], EPS);
        uval = ee * rr;
    }
    if (k == 0) out[bid] = ll;
}

extern "C" void kernel_launch(void* const* d_in, const int* in_sizes, int n_in,
                              void* d_out, int out_size, void* d_ws, size_t ws_size,
                              hipStream_t stream) {
    const float* emis  = (const float*)d_in[0];  // (L, M, B, Q)
    const float* A     = (const float*)d_in[1];  // (M, Q, Q)
    const float* initd = (const float*)d_in[2];  // (M, Q)
    float* out = (float*)d_out;                  // (M, B)

    const size_t wsNeeded = (size_t)M * CHUNKS * NTH * 16;  // 1 MB
    if (ws_size < wsNeeded) {
        hipLaunchKernelGGL(hmm_forward_fb, dim3(M * B), dim3(512), 0, stream,
                           emis, A, initd, out);
        return;
    }

    uint4* wsA = (uint4*)d_ws;
    (void)hipFuncSetAttribute((const void*)hmm_fwd,
                              hipFuncAttributeMaxDynamicSharedMemorySize,
                              SMEM_BYTES);
    hipLaunchKernelGGL(pack_A, dim3(M * CHUNKS * NTH / 256), dim3(256), 0,
                       stream, A, wsA);
    hipLaunchKernelGGL(hmm_fwd, dim3(M * B), dim3(NTH), SMEM_BYTES, stream,
                       emis, wsA, initd, out);
}